// Round 1
// baseline (586.663 us; speedup 1.0000x reference)
//
#include <hip/hip_runtime.h>

#define NPTS   262144
#define NBALLS 8192
#define MSZ    32

typedef unsigned short u16;
typedef __attribute__((ext_vector_type(8))) unsigned short u16x8;
typedef __attribute__((ext_vector_type(4))) unsigned short u16x4;
typedef __attribute__((ext_vector_type(8))) __bf16 bf16x8;
typedef __attribute__((ext_vector_type(4))) float f32x4;

__device__ inline u16 f2bf(float f) {
    unsigned u = __builtin_bit_cast(unsigned, f);
    u += 0x7fffu + ((u >> 16) & 1u);           // RNE
    return (u16)(u >> 16);
}

__device__ inline f32x4 mfma16x16x32(u16x8 a, u16x8 b, f32x4 c) {
    return __builtin_amdgcn_mfma_f32_16x16x32_bf16(
        __builtin_bit_cast(bf16x8, a), __builtin_bit_cast(bf16x8, b), c, 0, 0, 0);
}

__device__ inline void gload_lds16(const u16* g, u16* l) {
    __builtin_amdgcn_global_load_lds(
        (const __attribute__((address_space(1))) void*)g,
        (__attribute__((address_space(3))) void*)l, 16, 0, 0);
}

// ---------------- K0: weight prep (permute + transpose + bf16) ----------------
// new qkv col index cp = k*256 + h*32 + e  <->  orig col = h*96 + e*3 + k
__global__ __launch_bounds__(256) void k0_wprep(const float* __restrict__ w_qkv,
                                                const float* __restrict__ b_qkv,
                                                const float* __restrict__ w_proj,
                                                u16* __restrict__ wqkvT,
                                                u16* __restrict__ wprojT,
                                                float* __restrict__ bq) {
    int idx = blockIdx.x * 256 + threadIdx.x;
    if (idx < 768 * 256) {
        int cp = idx >> 8, r = idx & 255;
        int k = cp >> 8, rem = cp & 255, h = rem >> 5, e = rem & 31;
        int orig = h * 96 + e * 3 + k;
        wqkvT[cp * 256 + r] = f2bf(w_qkv[r * 768 + orig]);
        if (r == 0) bq[cp] = b_qkv[orig];
    } else {
        int i2 = idx - 768 * 256;
        if (i2 < 256 * 256) {
            int c = i2 >> 8, r = i2 & 255;
            wprojT[c * 256 + r] = f2bf(w_proj[r * 256 + c]);
        }
    }
}

// ---------------- K0b: xp = bf16(x + rel@w_pe + b_pe), one block per ball ----
__global__ __launch_bounds__(256) void k0b_xp(const float* __restrict__ x,
                                              const float* __restrict__ pos,
                                              const float* __restrict__ w_pe,
                                              const float* __restrict__ b_pe,
                                              u16* __restrict__ xp) {
    int ball = blockIdx.x, t = threadIdx.x;
    __shared__ float ps[MSZ][3];
    __shared__ float ctr[3];
    if (t < MSZ * 3) ((float*)ps)[t] = pos[(size_t)ball * (MSZ * 3) + t];
    __syncthreads();
    if (t < 3) {
        float s = 0.f;
#pragma unroll
        for (int j = 0; j < MSZ; ++j) s += ps[j][t];
        ctr[t] = s * (1.0f / MSZ);
    }
    __syncthreads();
    int c4 = (t & 63) * 4;
    float4 w0 = *(const float4*)&w_pe[c4];
    float4 w1 = *(const float4*)&w_pe[256 + c4];
    float4 w2 = *(const float4*)&w_pe[512 + c4];
    float4 bp = *(const float4*)&b_pe[c4];
#pragma unroll
    for (int mi = (t >> 6); mi < MSZ; mi += 4) {
        float rx = ps[mi][0] - ctr[0], ry = ps[mi][1] - ctr[1], rz = ps[mi][2] - ctr[2];
        size_t row = (size_t)ball * MSZ + mi;
        float4 xv = *(const float4*)&x[row * 256 + c4];
        u16x4 o;
        o.x = f2bf(xv.x + rx * w0.x + ry * w1.x + rz * w2.x + bp.x);
        o.y = f2bf(xv.y + rx * w0.y + ry * w1.y + rz * w2.y + bp.y);
        o.z = f2bf(xv.z + rx * w0.z + ry * w1.z + rz * w2.z + bp.z);
        o.w = f2bf(xv.w + rx * w0.w + ry * w1.w + rz * w2.w + bp.w);
        *(u16x4*)&xp[row * 256 + c4] = o;
    }
}

// ---------------- K1: QKV GEMM  (N=262144 x 768, K=256), bf16 MFMA ----------
__global__ __launch_bounds__(256) void k1_qkv(const u16* __restrict__ xp,
                                              const u16* __restrict__ wqkvT,
                                              const float* __restrict__ bq,
                                              u16* __restrict__ qkv) {
    __shared__ __align__(16) u16 As[2][128 * 64];
    __shared__ __align__(16) u16 Bs[2][128 * 64];
    int id = blockIdx.x;
    int wk = (id >> 3) + (id & 7) * 1536;       // bijective XCD swizzle (12288 % 8 == 0)
    int ct = wk % 6, rt = wk / 6;
    int t = threadIdx.x;
    int lane = t & 63, wv = t >> 6;
    int r15 = lane & 15, g4 = lane >> 4;
    int wr = wv >> 1, wc = wv & 1;
    int rowbase = rt * 128, colbase = ct * 128;

    f32x4 acc[4][4];
#pragma unroll
    for (int i = 0; i < 4; ++i)
#pragma unroll
        for (int j = 0; j < 4; ++j) acc[i][j] = (f32x4){0.f, 0.f, 0.f, 0.f};

    // prologue stage kt=0
#pragma unroll
    for (int i = 0; i < 4; ++i) {
        int chunk = i * 256 + t;
        int row = chunk >> 3, kc = chunk & 7;
        gload_lds16(&xp[(size_t)(rowbase + row) * 256 + kc * 8],
                    &As[0][(i * 256 + wv * 64) * 8]);
        gload_lds16(&wqkvT[(size_t)(colbase + row) * 256 + kc * 8],
                    &Bs[0][(i * 256 + wv * 64) * 8]);
    }
    __syncthreads();

    for (int kt = 0; kt < 4; ++kt) {
        int cur = kt & 1;
        if (kt < 3) {
            int k0 = (kt + 1) * 64;
#pragma unroll
            for (int i = 0; i < 4; ++i) {
                int chunk = i * 256 + t;
                int row = chunk >> 3, kc = chunk & 7;
                gload_lds16(&xp[(size_t)(rowbase + row) * 256 + k0 + kc * 8],
                            &As[cur ^ 1][(i * 256 + wv * 64) * 8]);
                gload_lds16(&wqkvT[(size_t)(colbase + row) * 256 + k0 + kc * 8],
                            &Bs[cur ^ 1][(i * 256 + wv * 64) * 8]);
            }
        }
#pragma unroll
        for (int ks = 0; ks < 2; ++ks) {
            u16x8 a[4], b[4];
#pragma unroll
            for (int i = 0; i < 4; ++i)
                a[i] = *(const u16x8*)&As[cur][(wr * 64 + i * 16 + r15) * 64 + ks * 32 + g4 * 8];
#pragma unroll
            for (int j = 0; j < 4; ++j)
                b[j] = *(const u16x8*)&Bs[cur][(wc * 64 + j * 16 + r15) * 64 + ks * 32 + g4 * 8];
#pragma unroll
            for (int i = 0; i < 4; ++i)
#pragma unroll
                for (int j = 0; j < 4; ++j)
                    acc[i][j] = mfma16x16x32(a[i], b[j], acc[i][j]);
        }
        __syncthreads();
    }

#pragma unroll
    for (int j = 0; j < 4; ++j) {
        int col = colbase + wc * 64 + j * 16 + r15;
        float bias = bq[col];
#pragma unroll
        for (int i = 0; i < 4; ++i) {
            int row0 = rowbase + wr * 64 + i * 16 + g4 * 4;
#pragma unroll
            for (int r = 0; r < 4; ++r)
                qkv[(size_t)(row0 + r) * 768 + col] = f2bf(acc[i][j][r] + bias);
        }
    }
}

// ---------------- K2: per-ball attention, writes result over q-region -------
__global__ __launch_bounds__(256) void k2_attn(const float* __restrict__ pos,
                                               const float* __restrict__ sigma,
                                               u16* qkv) {
    int ball = blockIdx.x, t = threadIdx.x;
    __shared__ float ps[MSZ][3];
    __shared__ float dist_s[MSZ][33];
    __shared__ __align__(16) u16 V_s[MSZ][256];
    __shared__ __align__(16) u16 P_s[4][MSZ][40];
    if (t < MSZ * 3) ((float*)ps)[t] = pos[(size_t)ball * (MSZ * 3) + t];
    __syncthreads();
    for (int p = t; p < 1024; p += 256) {
        int m = p >> 5, k = p & 31;
        float dx = ps[m][0] - ps[k][0], dy = ps[m][1] - ps[k][1], dz = ps[m][2] - ps[k][2];
        dist_s[m][k] = sqrtf(fmaxf(dx * dx + dy * dy + dz * dz, 1e-12f));
    }
    const size_t ballrow = (size_t)ball * MSZ * 768;
    // stage V (cols 512..767) with XOR swizzle on col bits 4-5 keyed by row bits 3-4
#pragma unroll
    for (int i = 0; i < 4; ++i) {
        int c = i * 256 + t;
        int row = c >> 5, col8 = (c & 31) * 8;
        int cs = col8 ^ (((row >> 3) & 3) << 4);
        *(u16x8*)&V_s[row][cs] = *(const u16x8*)&qkv[ballrow + (size_t)row * 768 + 512 + col8];
    }
    __syncthreads();

    int lane = t & 63, wv = t >> 6;
    int r15 = lane & 15, g4 = lane >> 4;
    const float scale = 0.17677669529663687f;   // 1/sqrt(32)

#pragma unroll
    for (int hh = 0; hh < 2; ++hh) {
        int h = wv * 2 + hh;
        float sig = sigma[h];
        u16x8 aq[2], bk[2];
#pragma unroll
        for (int i = 0; i < 2; ++i) {
            aq[i] = *(const u16x8*)&qkv[ballrow + (size_t)(i * 16 + r15) * 768 + h * 32 + g4 * 8];
            bk[i] = *(const u16x8*)&qkv[ballrow + (size_t)(i * 16 + r15) * 768 + 256 + h * 32 + g4 * 8];
        }
        f32x4 s[2][2];
#pragma unroll
        for (int i = 0; i < 2; ++i)
#pragma unroll
            for (int j = 0; j < 2; ++j) s[i][j] = (f32x4){0.f, 0.f, 0.f, 0.f};
#pragma unroll
        for (int i = 0; i < 2; ++i)
#pragma unroll
            for (int j = 0; j < 2; ++j)
                s[i][j] = mfma16x16x32(aq[i], bk[j], s[i][j]);

        // scale + bias + row softmax (rows live on (g4,r); cols across r15 x 2 frags)
#pragma unroll
        for (int i = 0; i < 2; ++i) {
#pragma unroll
            for (int r = 0; r < 4; ++r) {
                int row = i * 16 + g4 * 4 + r;
                float v0 = s[i][0][r] * scale + sig * dist_s[row][r15];
                float v1 = s[i][1][r] * scale + sig * dist_s[row][16 + r15];
                float m = fmaxf(v0, v1);
                m = fmaxf(m, __shfl_xor(m, 1));
                m = fmaxf(m, __shfl_xor(m, 2));
                m = fmaxf(m, __shfl_xor(m, 4));
                m = fmaxf(m, __shfl_xor(m, 8));
                float e0 = __expf(v0 - m), e1 = __expf(v1 - m);
                float su = e0 + e1;
                su += __shfl_xor(su, 1);
                su += __shfl_xor(su, 2);
                su += __shfl_xor(su, 4);
                su += __shfl_xor(su, 8);
                float rin = 1.0f / su;
                P_s[wv][row][r15]      = f2bf(e0 * rin);
                P_s[wv][row][16 + r15] = f2bf(e1 * rin);
            }
        }
        // PV
        u16x8 pa[2];
#pragma unroll
        for (int i = 0; i < 2; ++i)
            pa[i] = *(const u16x8*)&P_s[wv][i * 16 + r15][g4 * 8];
        u16x8 bv[2];
#pragma unroll
        for (int j = 0; j < 2; ++j) {
#pragma unroll
            for (int jj = 0; jj < 8; ++jj) {
                int kp = g4 * 8 + jj;
                int colv = h * 32 + j * 16 + r15;
                bv[j][jj] = V_s[kp][colv ^ (((kp >> 3) & 3) << 4)];
            }
        }
        f32x4 o[2][2];
#pragma unroll
        for (int i = 0; i < 2; ++i)
#pragma unroll
            for (int j = 0; j < 2; ++j) o[i][j] = (f32x4){0.f, 0.f, 0.f, 0.f};
#pragma unroll
        for (int i = 0; i < 2; ++i)
#pragma unroll
            for (int j = 0; j < 2; ++j)
                o[i][j] = mfma16x16x32(pa[i], bv[j], o[i][j]);
#pragma unroll
        for (int i = 0; i < 2; ++i)
#pragma unroll
            for (int j = 0; j < 2; ++j)
#pragma unroll
                for (int r = 0; r < 4; ++r) {
                    int row = i * 16 + g4 * 4 + r;
                    int col = h * 32 + j * 16 + r15;
                    qkv[ballrow + (size_t)row * 768 + col] = f2bf(o[i][j][r]);
                }
    }
}

// ---------------- K3: proj GEMM (N x 256, K=256), fp32 out ------------------
__global__ __launch_bounds__(256) void k3_proj(const u16* __restrict__ attn,   // stride 768, cols 0..255
                                               const u16* __restrict__ wprojT,
                                               const float* __restrict__ bp,
                                               float* __restrict__ out) {
    __shared__ __align__(16) u16 As[2][128 * 64];
    __shared__ __align__(16) u16 Bs[2][128 * 64];
    int id = blockIdx.x;
    int wk = (id >> 3) + (id & 7) * 512;        // 4096 blocks, 4096%8==0
    int ct = wk & 1, rt = wk >> 1;
    int t = threadIdx.x;
    int lane = t & 63, wv = t >> 6;
    int r15 = lane & 15, g4 = lane >> 4;
    int wr = wv >> 1, wc = wv & 1;
    int rowbase = rt * 128, colbase = ct * 128;

    f32x4 acc[4][4];
#pragma unroll
    for (int i = 0; i < 4; ++i)
#pragma unroll
        for (int j = 0; j < 4; ++j) acc[i][j] = (f32x4){0.f, 0.f, 0.f, 0.f};

#pragma unroll
    for (int i = 0; i < 4; ++i) {
        int chunk = i * 256 + t;
        int row = chunk >> 3, kc = chunk & 7;
        gload_lds16(&attn[(size_t)(rowbase + row) * 768 + kc * 8],
                    &As[0][(i * 256 + wv * 64) * 8]);
        gload_lds16(&wprojT[(size_t)(colbase + row) * 256 + kc * 8],
                    &Bs[0][(i * 256 + wv * 64) * 8]);
    }
    __syncthreads();

    for (int kt = 0; kt < 4; ++kt) {
        int cur = kt & 1;
        if (kt < 3) {
            int k0 = (kt + 1) * 64;
#pragma unroll
            for (int i = 0; i < 4; ++i) {
                int chunk = i * 256 + t;
                int row = chunk >> 3, kc = chunk & 7;
                gload_lds16(&attn[(size_t)(rowbase + row) * 768 + k0 + kc * 8],
                            &As[cur ^ 1][(i * 256 + wv * 64) * 8]);
                gload_lds16(&wprojT[(size_t)(colbase + row) * 256 + k0 + kc * 8],
                            &Bs[cur ^ 1][(i * 256 + wv * 64) * 8]);
            }
        }
#pragma unroll
        for (int ks = 0; ks < 2; ++ks) {
            u16x8 a[4], b[4];
#pragma unroll
            for (int i = 0; i < 4; ++i)
                a[i] = *(const u16x8*)&As[cur][(wr * 64 + i * 16 + r15) * 64 + ks * 32 + g4 * 8];
#pragma unroll
            for (int j = 0; j < 4; ++j)
                b[j] = *(const u16x8*)&Bs[cur][(wc * 64 + j * 16 + r15) * 64 + ks * 32 + g4 * 8];
#pragma unroll
            for (int i = 0; i < 4; ++i)
#pragma unroll
                for (int j = 0; j < 4; ++j)
                    acc[i][j] = mfma16x16x32(a[i], b[j], acc[i][j]);
        }
        __syncthreads();
    }

#pragma unroll
    for (int j = 0; j < 4; ++j) {
        int col = colbase + wc * 64 + j * 16 + r15;
        float bias = bp[col];
#pragma unroll
        for (int i = 0; i < 4; ++i) {
            int row0 = rowbase + wr * 64 + i * 16 + g4 * 4;
#pragma unroll
            for (int r = 0; r < 4; ++r)
                out[(size_t)(row0 + r) * 256 + col] = acc[i][j][r] + bias;
        }
    }
}

extern "C" void kernel_launch(void* const* d_in, const int* in_sizes, int n_in,
                              void* d_out, int out_size, void* d_ws, size_t ws_size,
                              hipStream_t stream) {
    (void)in_sizes; (void)n_in; (void)out_size; (void)ws_size;
    const float* x      = (const float*)d_in[0];
    const float* pos    = (const float*)d_in[1];
    const float* w_qkv  = (const float*)d_in[2];
    const float* b_qkv  = (const float*)d_in[3];
    const float* w_pe   = (const float*)d_in[4];
    const float* b_pe   = (const float*)d_in[5];
    const float* w_proj = (const float*)d_in[6];
    const float* b_proj = (const float*)d_in[7];
    const float* sigma  = (const float*)d_in[8];
    float* out = (float*)d_out;

    u16* qkv    = (u16*)d_ws;                       // N*768 bf16 = 402.7 MB
    u16* wqkvT  = qkv + (size_t)NPTS * 768;
    u16* wprojT = wqkvT + 768 * 256;
    float* bq   = (float*)(wprojT + 256 * 256);
    u16* xp     = (u16*)d_out;                      // scratch: first N*256 bf16, overwritten by k3

    k0_wprep<<<1024, 256, 0, stream>>>(w_qkv, b_qkv, w_proj, wqkvT, wprojT, bq);
    k0b_xp<<<NBALLS, 256, 0, stream>>>(x, pos, w_pe, b_pe, xp);
    k1_qkv<<<12288, 256, 0, stream>>>(xp, wqkvT, bq, qkv);
    k2_attn<<<NBALLS, 256, 0, stream>>>(pos, sigma, qkv);
    k3_proj<<<4096, 256, 0, stream>>>(qkv, wprojT, b_proj, out);
}